// Round 9
// baseline (305.213 us; speedup 1.0000x reference)
//
#include <hip/hip_runtime.h>
#include <math.h>

// PathFusionEmbedding: B=512, T=100, L=256, D=128, DEPTH=8 (P=9).
// Split-bf16 MFMA (h*W = hh*Wh + hh*Wl + hl*Wh; x*W single-term bf16).
// R10-R17: six attempts to make B register/AGPR-resident against the
// backend's 128-VGPR occupancy policy all failed (remat refetch = 2.0 GB
// L2 = 28 TB/s ceiling -> 74 us; explicit-load variants spill 28-130 MB).
// R18: stop fighting. Split by level-size:
//  - trunk (levels 0-6): 200 half-tree blocks, 8 B-stream iters total
//    (aggregate 614 MB vs 2.0 GB), R12's PROVEN remat MFMA core, h/c
//    single-buffered in LDS (reads hoisted pre-barrier), h6/c6 -> global.
//  - gemm7/gemm8 (levels 7-8 = 75% of nodes): true GEMM dispatches,
//    BM=32 rows/block, B streamed ONCE PER BLOCK in per-kb 32 KB chunks
//    through LDS (hi and lo as separate sub-phases; 56 KB LDS, 2 blk/CU).
//    B traffic: L7 400x448KB + L8 800x448KB ~ 0.5 GB total.
// h6g/c6g alias the h8 region (dead before gemm8 overwrites) -> ws usage
// unchanged from the proven layout.

#define B_N 512
#define T_N 100
#define L_N 256
#define D_N 128
#define NPT 511

typedef __attribute__((ext_vector_type(8))) short short8;
typedef __attribute__((ext_vector_type(4))) float f32x4;
typedef __attribute__((ext_vector_type(4))) unsigned short ushort4v;

__device__ __forceinline__ unsigned short f2bf(float f) {
    unsigned u = __float_as_uint(f);
    return (unsigned short)((u + 0x7FFFu + ((u >> 16) & 1u)) >> 16);
}
__device__ __forceinline__ float bf2f(unsigned short b) {
    return __uint_as_float(((unsigned)b) << 16);
}
__device__ __forceinline__ float fsigmoid(float x) {
    return __builtin_amdgcn_rcpf(1.f + __builtin_amdgcn_exp2f(-1.44269504f * x));
}
__device__ __forceinline__ float ftanh(float x) {
    return 1.f - 2.f * __builtin_amdgcn_rcpf(1.f + __builtin_amdgcn_exp2f(2.88539009f * x));
}

// ---------------- weight pack + bias prep ----------------
// W'[n'][k] = k<128 ? w_ih[n'][k] : w_hh[n'][k-128]   (n' = gate*128 + j)
// Frag order: kb=k>>5, quad=(k&31)>>3, e=k&7, tn=n'>>4, lane=quad*16+(n'&15);
// Bhi[((kb*32+tn)*64+lane)*8+e]; Blo only for k>=128. Chunk kb is a
// CONTIGUOUS 32 KB span -> cheap LDS staging in the gemm kernels.
__global__ __launch_bounds__(256) void pack_kernel(const float* __restrict__ w_ih,
                                                   const float* __restrict__ w_hh,
                                                   const float* __restrict__ b_ih,
                                                   const float* __restrict__ b_hh,
                                                   unsigned short* __restrict__ Bhi,
                                                   unsigned short* __restrict__ Blo,
                                                   float* __restrict__ bias) {
    const int idx = blockIdx.x * 256 + threadIdx.x;   // 131072 = 512 n' x 256 k
    const int k  = idx & 255;
    const int np = idx >> 8;
    const float val = (k < 128) ? w_ih[(size_t)np * 128 + k]
                                : w_hh[(size_t)np * 128 + (k - 128)];
    const unsigned short hi = f2bf(val);
    const int kb = k >> 5, krel = k & 31, quad = krel >> 3, e = krel & 7;
    const int tn = np >> 4, col = np & 15, lane = quad * 16 + col;
    Bhi[(((size_t)kb * 32 + tn) * 64 + lane) * 8 + e] = hi;
    if (kb >= 4) {
        const unsigned short lo = f2bf(val - bf2f(hi));
        Blo[((((size_t)kb - 4) * 32 + tn) * 64 + lane) * 8 + e] = lo;
    }
    if (k == 0) bias[np] = b_ih[np] + b_hh[np];
}

// ---------------- trunk: levels 0..6, one block per (tree, half) ----------
// Block covers half-tree rows [s*2^(d-1),(s+1)*2^(d-1)) at level d>=1;
// local parent of local row m is always m>>1 (root local 0). 8 B-stream
// iterations per block (1 per level + 2 at L6). h/c single-buffered in LDS:
// all reads (stage h-part + hoisted cpre) happen PRE-barrier, writes POST.
__global__ __launch_bounds__(512, 4) void trunk_kernel(
    const float* __restrict__ node_emb,
    const unsigned short* __restrict__ Bhi,
    const unsigned short* __restrict__ Blo,
    const float* __restrict__ bias,
    float* __restrict__ h6g, float* __restrict__ c6g)
{
    __shared__ float hbuf[32][132];               // 16.9 KB
    __shared__ float cbuf[32][132];               // 16.9 KB
    __shared__ unsigned short AhiF[8 * 2 * 512];  // 16 KB (2 tiles)
    __shared__ unsigned short AloF[4 * 2 * 512];  //  8 KB
    // Total 58368 B -> 2 blocks/CU.

    const int t    = blockIdx.x >> 1;
    const int s    = blockIdx.x & 1;
    const int tid  = threadIdx.x;
    const int widx = tid >> 6;
    const int lane = tid & 63;
    const int ml   = lane & 15;
    const int quad = lane >> 4;
    const int j    = widx * 16 + ml;

    const float bi = bias[j];
    const float bf = bias[128 + j];
    const float bg = bias[256 + j];
    const float bo = bias[384 + j];

    const short8* Bh8 = reinterpret_cast<const short8*>(Bhi);
    const short8* Bl8 = reinterpret_cast<const short8*>(Blo);
    const short8* Ah8 = reinterpret_cast<const short8*>(AhiF);
    const short8* Al8 = reinterpret_cast<const short8*>(AloF);

    for (int d = 0; d <= 6; ++d) {
        const int rows = (d == 0) ? 1 : (1 << (d - 1));

        // ---- PRE-barrier reads: hoisted cpre + A staging (reads hbuf) ----
        float cpre[2][4];
        #pragma unroll
        for (int mt = 0; mt < 2; ++mt)
            #pragma unroll
            for (int rr = 0; rr < 4; ++rr) {
                int m = mt * 16 + quad * 4 + rr;
                if (m > rows - 1) m = rows - 1;
                cpre[mt][rr] = (d == 0) ? 0.f : cbuf[m >> 1][j];
            }

        #pragma unroll
        for (int h2 = 0; h2 < 4; ++h2) {
            const int r  = tid >> 4;              // 0..31
            const int kq = tid & 15;
            const int k  = (kq + h2 * 16) * 4;    // 0..252
            int p = r; if (p > rows - 1) p = rows - 1;
            float4 v;
            if (k < 128) {
                const int pg   = (d == 0) ? 0 : ((s << (d - 1)) + p);
                const int node = (1 << d) - 1 + pg;
                v = *reinterpret_cast<const float4*>(
                        node_emb + (size_t)(t * NPT + node) * D_N + k);
            } else if (d == 0) {
                v = make_float4(0.f, 0.f, 0.f, 0.f);
            } else {
                v = *reinterpret_cast<const float4*>(&hbuf[p >> 1][k - 128]);
            }
            const int kb = k >> 5, qk = (k & 31) >> 3, e0 = k & 4;
            const int mt = r >> 4, mlr = r & 15;
            const ushort4v hv = { f2bf(v.x), f2bf(v.y), f2bf(v.z), f2bf(v.w) };
            *reinterpret_cast<ushort4v*>(
                &AhiF[((kb * 2 + mt) * 64 + qk * 16 + mlr) * 8 + e0]) = hv;
            if (k >= 128) {
                const ushort4v lv = { f2bf(v.x - bf2f(hv.x)), f2bf(v.y - bf2f(hv.y)),
                                      f2bf(v.z - bf2f(hv.z)), f2bf(v.w - bf2f(hv.w)) };
                *reinterpret_cast<ushort4v*>(
                    &AloF[(((kb - 4) * 2 + mt) * 64 + qk * 16 + mlr) * 8 + e0]) = lv;
            }
        }
        __syncthreads();

        // ---- MFMA: sequential M-tiles, R12-proven remat B-stream ----
        const int nmt = (rows > 16) ? 2 : 1;
        for (int mt = 0; mt < nmt; ++mt) {
            f32x4 acc[4];
            #pragma unroll
            for (int g = 0; g < 4; ++g) acc[g] = (f32x4)0.f;
            #pragma unroll
            for (int kb = 0; kb < 8; ++kb) {
                const short8 ah = Ah8[(kb * 2 + mt) * 64 + lane];
                short8 al;
                if (kb >= 4) al = Al8[((kb - 4) * 2 + mt) * 64 + lane];
                #pragma unroll
                for (int g = 0; g < 4; ++g) {
                    const short8 bh = Bh8[(kb * 32 + g * 8 + widx) * 64 + lane];
                    acc[g] = __builtin_amdgcn_mfma_f32_16x16x32_bf16(ah, bh, acc[g], 0, 0, 0);
                    if (kb >= 4) {
                        const short8 bl = Bl8[((kb - 4) * 32 + g * 8 + widx) * 64 + lane];
                        acc[g] = __builtin_amdgcn_mfma_f32_16x16x32_bf16(ah, bl, acc[g], 0, 0, 0);
                        acc[g] = __builtin_amdgcn_mfma_f32_16x16x32_bf16(al, bh, acc[g], 0, 0, 0);
                    }
                }
            }
            #pragma unroll
            for (int rr = 0; rr < 4; ++rr) {
                const int m = mt * 16 + quad * 4 + rr;
                if (m < rows) {
                    const float ig = fsigmoid(acc[0][rr] + bi);
                    const float fg = fsigmoid(acc[1][rr] + bf);
                    const float gv = ftanh(acc[2][rr] + bg);
                    const float og = fsigmoid(acc[3][rr] + bo);
                    const float cn = fg * cpre[mt][rr] + ig * gv;
                    const float hn = og * ftanh(cn);
                    hbuf[m][j] = hn;
                    cbuf[m][j] = cn;
                    if (d == 6) {
                        const size_t row = (size_t)(t * 64 + s * 32 + m) * D_N + j;
                        h6g[row] = hn;
                        c6g[row] = cn;
                    }
                }
            }
        }
        __syncthreads();
    }
}

// ---------------- gemm: one level (7 or 8) as a tiled GEMM ----------------
// BM=32 rows/block. B streamed once per block: per-kb 32 KB chunk copied
// global->LDS; hi and lo chunks as separate sub-phases sharing one buffer.
// acc[2][4] + bh[4] ~ 90 live VGPRs. LDS 56 KB -> 2 blocks/CU.
__global__ __launch_bounds__(512, 4) void gemm_kernel(
    const float* __restrict__ node_emb,
    const unsigned short* __restrict__ Bhi,
    const unsigned short* __restrict__ Blo,
    const float* __restrict__ bias,
    const float* __restrict__ hsrc,
    const float* __restrict__ csrc,
    float* __restrict__ hdst,
    float* __restrict__ cdst,          // null for level 8
    const int rpt_sh,                  // log2(rows per tree): 7 or 8
    const int node_off)                // 127 or 255
{
    __shared__ unsigned short AhiF[8 * 2 * 512];  // 16 KB
    __shared__ unsigned short AloF[4 * 2 * 512];  //  8 KB
    __shared__ int4 BL[2048];                     // 32 KB B chunk
    // Total 57344 B -> 2 blocks/CU.

    const int tid  = threadIdx.x;
    const int widx = tid >> 6;
    const int lane = tid & 63;
    const int ml   = lane & 15;
    const int quad = lane >> 4;
    const int j    = widx * 16 + ml;

    const int b0 = blockIdx.x * 32;               // global row base
    const int t  = b0 >> rpt_sh;
    const int q0 = b0 & ((1 << rpt_sh) - 1);
    const size_t nbase = (size_t)(t * NPT + node_off) * D_N;  // + q*128
    const size_t pbase = ((size_t)t << (rpt_sh - 1)) * D_N;   // + (q>>1)*128

    const float bi = bias[j];
    const float bf = bias[128 + j];
    const float bg = bias[256 + j];
    const float bo = bias[384 + j];

    const short8* Ah8 = reinterpret_cast<const short8*>(AhiF);
    const short8* Al8 = reinterpret_cast<const short8*>(AloF);
    const short8* BL8 = reinterpret_cast<const short8*>(BL);

    // ---- stage A (32 rows): x from node_emb, h-part split from hsrc ----
    #pragma unroll
    for (int h2 = 0; h2 < 4; ++h2) {
        const int r  = tid >> 4;                  // 0..31
        const int kq = tid & 15;
        const int k  = (kq + h2 * 16) * 4;
        const int q  = q0 + r;
        float4 v;
        if (k < 128)
            v = *reinterpret_cast<const float4*>(node_emb + nbase + (size_t)q * D_N + k);
        else
            v = *reinterpret_cast<const float4*>(hsrc + pbase + (size_t)(q >> 1) * D_N + (k - 128));
        const int kb = k >> 5, qk = (k & 31) >> 3, e0 = k & 4;
        const int mt = r >> 4, mlr = r & 15;
        const ushort4v hv = { f2bf(v.x), f2bf(v.y), f2bf(v.z), f2bf(v.w) };
        *reinterpret_cast<ushort4v*>(
            &AhiF[((kb * 2 + mt) * 64 + qk * 16 + mlr) * 8 + e0]) = hv;
        if (k >= 128) {
            const ushort4v lv = { f2bf(v.x - bf2f(hv.x)), f2bf(v.y - bf2f(hv.y)),
                                  f2bf(v.z - bf2f(hv.z)), f2bf(v.w - bf2f(hv.w)) };
            *reinterpret_cast<ushort4v*>(
                &AloF[(((kb - 4) * 2 + mt) * 64 + qk * 16 + mlr) * 8 + e0]) = lv;
        }
    }

    float cpre[2][4];
    #pragma unroll
    for (int mt = 0; mt < 2; ++mt)
        #pragma unroll
        for (int rr = 0; rr < 4; ++rr) {
            const int q = q0 + mt * 16 + quad * 4 + rr;
            cpre[mt][rr] = csrc[pbase + (size_t)(q >> 1) * D_N + j];
        }
    __syncthreads();

    f32x4 acc[2][4];
    #pragma unroll
    for (int mt = 0; mt < 2; ++mt)
        #pragma unroll
        for (int g = 0; g < 4; ++g) acc[mt][g] = (f32x4)0.f;

    #pragma unroll
    for (int kb = 0; kb < 8; ++kb) {
        // ---- HI sub-phase: Bhi chunk kb -> LDS; ah*bh (+ al*bh) ----
        {
            const int4* src = reinterpret_cast<const int4*>(Bhi) + kb * 2048;
            #pragma unroll
            for (int c = 0; c < 4; ++c) BL[tid + c * 512] = src[tid + c * 512];
        }
        __syncthreads();
        {
            short8 bh[4];
            #pragma unroll
            for (int g = 0; g < 4; ++g) bh[g] = BL8[(g * 8 + widx) * 64 + lane];
            #pragma unroll
            for (int mt = 0; mt < 2; ++mt) {
                const short8 ah = Ah8[(kb * 2 + mt) * 64 + lane];
                #pragma unroll
                for (int g = 0; g < 4; ++g)
                    acc[mt][g] = __builtin_amdgcn_mfma_f32_16x16x32_bf16(ah, bh[g], acc[mt][g], 0, 0, 0);
                if (kb >= 4) {
                    const short8 al = Al8[((kb - 4) * 2 + mt) * 64 + lane];
                    #pragma unroll
                    for (int g = 0; g < 4; ++g)
                        acc[mt][g] = __builtin_amdgcn_mfma_f32_16x16x32_bf16(al, bh[g], acc[mt][g], 0, 0, 0);
                }
            }
        }
        __syncthreads();
        // ---- LO sub-phase (kb>=4): Blo chunk -> LDS; ah*bl ----
        if (kb >= 4) {
            {
                const int4* src = reinterpret_cast<const int4*>(Blo) + (kb - 4) * 2048;
                #pragma unroll
                for (int c = 0; c < 4; ++c) BL[tid + c * 512] = src[tid + c * 512];
            }
            __syncthreads();
            {
                short8 bl[4];
                #pragma unroll
                for (int g = 0; g < 4; ++g) bl[g] = BL8[(g * 8 + widx) * 64 + lane];
                #pragma unroll
                for (int mt = 0; mt < 2; ++mt) {
                    const short8 ah = Ah8[(kb * 2 + mt) * 64 + lane];
                    #pragma unroll
                    for (int g = 0; g < 4; ++g)
                        acc[mt][g] = __builtin_amdgcn_mfma_f32_16x16x32_bf16(ah, bl[g], acc[mt][g], 0, 0, 0);
                }
            }
            __syncthreads();
        }
    }

    // ---- LSTM epilogue ----
    #pragma unroll
    for (int mt = 0; mt < 2; ++mt)
        #pragma unroll
        for (int rr = 0; rr < 4; ++rr) {
            const int m  = mt * 16 + quad * 4 + rr;
            const float ig = fsigmoid(acc[mt][0][rr] + bi);
            const float fg = fsigmoid(acc[mt][1][rr] + bf);
            const float gv = ftanh(acc[mt][2][rr] + bg);
            const float og = fsigmoid(acc[mt][3][rr] + bo);
            const float cn = fg * cpre[mt][rr] + ig * gv;
            const float hn = og * ftanh(cn);
            const size_t row = (size_t)(b0 + m) * D_N + j;
            hdst[row] = hn;
            if (cdst) cdst[row] = cn;
        }
}

// ---------------- fused leaf-extract + gather ----------------
__global__ __launch_bounds__(256) void gather_kernel(const float* __restrict__ cross,
                                                     const float* __restrict__ h8,
                                                     float* __restrict__ out) {
    const int bt   = blockIdx.x * 4 + (threadIdx.x >> 6);
    const int lane = threadIdx.x & 63;
    const int t    = bt % T_N;
    const float4 v = reinterpret_cast<const float4*>(cross + (size_t)bt * L_N)[lane];
    int idx = -1;
    if      (v.x > 0.f) idx = lane * 4 + 0;
    else if (v.y > 0.f) idx = lane * 4 + 1;
    else if (v.z > 0.f) idx = lane * 4 + 2;
    else if (v.w > 0.f) idx = lane * 4 + 3;
    const unsigned long long m = __ballot(idx >= 0);
    int lf = -1;
    if (m != 0ULL) {
        const int first = __builtin_ctzll(m);
        lf = __shfl(idx, first);
    }
    float2 o = make_float2(0.f, 0.f);
    if (lf >= 0)
        o = reinterpret_cast<const float2*>(h8 + (size_t)(t * L_N + lf) * D_N)[lane];
    reinterpret_cast<float2*>(out + (size_t)bt * D_N)[lane] = o;
}

extern "C" void kernel_launch(void* const* d_in, const int* in_sizes, int n_in,
                              void* d_out, int out_size, void* d_ws, size_t ws_size,
                              hipStream_t stream) {
    const float* cross    = (const float*)d_in[0];
    const float* node_emb = (const float*)d_in[1];
    const float* w_ih     = (const float*)d_in[2];
    const float* w_hh     = (const float*)d_in[3];
    const float* b_ih     = (const float*)d_in[4];
    const float* b_hh     = (const float*)d_in[5];
    float* out = (float*)d_out;
    float* ws  = (float*)d_ws;

    // ws layout (floats) -- identical footprint to the proven layout:
    // h8[25600*128], h7g[12800*128], c7g[12800*128], bias[512],
    // Bhi[131072 u16], Blo[65536 u16].
    float* h8   = ws;
    float* h7g  = h8 + (size_t)25600 * D_N;
    float* c7g  = h7g + (size_t)12800 * D_N;
    float* bias = c7g + (size_t)12800 * D_N;
    unsigned short* Bhi = (unsigned short*)(bias + 512);
    unsigned short* Blo = Bhi + 131072;
    // h6g/c6g alias the FRONT of h8: dead once gemm7 finishes; gemm8
    // overwrites the region with final h8 values afterwards (stream order).
    float* c6g = h8;                               // rows [0, 6400)
    float* h6g = h8 + (size_t)6400 * D_N;          // rows [6400, 12800)

    pack_kernel<<<512, 256, 0, stream>>>(w_ih, w_hh, b_ih, b_hh, Bhi, Blo, bias);

    // levels 0..6: one block per (tree, half-tree)
    trunk_kernel<<<2 * T_N, 512, 0, stream>>>(node_emb, Bhi, Blo, bias, h6g, c6g);

    // level 7: M = 12800 rows, BM=32 -> 400 blocks
    gemm_kernel<<<400, 512, 0, stream>>>(node_emb, Bhi, Blo, bias,
                                         h6g, c6g, h7g, c7g, 7, 127);

    // level 8: M = 25600 rows -> 800 blocks (writes h8, incl. aliased front)
    gemm_kernel<<<800, 512, 0, stream>>>(node_emb, Bhi, Blo, bias,
                                         h7g, c7g, h8, nullptr, 8, 255);

    // fused leaf+gather
    gather_kernel<<<(B_N * T_N) / 4, 256, 0, stream>>>(cross, h8, out);
}

// Round 10
// 214.549 us; speedup vs baseline: 1.4226x; 1.4226x over previous
//
#include <hip/hip_runtime.h>
#include <math.h>

// PathFusionEmbedding: B=512, T=100, L=256, D=128, DEPTH=8 (P=9).
// Split-bf16 MFMA (h*W = hh*Wh + hh*Wl + hl*Wh; x*W single-term bf16).
// R10-R17: six attempts to make B register/AGPR-resident against the
// backend's 128-VGPR occupancy policy all failed (remat refetch = 2.0 GB
// L2 = 28 TB/s ceiling -> 74 us; explicit-load variants spill 28-130 MB).
// R18: level-split architecture (trunk L0-6 + gemm L7 + gemm L8, B through
// LDS for the big levels). Correct, but __launch_bounds__(512,4) let the
// allocator drop to the 64-VGPR tier -> massive spill/remat (VGPR=64,
// FETCH 213 MB, trunk 131-215 us).
// R19: the ONLY config that has ever produced the clean 128-VGPR tier this
// session is __launch_bounds__(512,2) (R12/R13: VGPR=128, zero scratch).
// Apply it to trunk and gemm. No other change.

#define B_N 512
#define T_N 100
#define L_N 256
#define D_N 128
#define NPT 511

typedef __attribute__((ext_vector_type(8))) short short8;
typedef __attribute__((ext_vector_type(4))) float f32x4;
typedef __attribute__((ext_vector_type(4))) unsigned short ushort4v;

__device__ __forceinline__ unsigned short f2bf(float f) {
    unsigned u = __float_as_uint(f);
    return (unsigned short)((u + 0x7FFFu + ((u >> 16) & 1u)) >> 16);
}
__device__ __forceinline__ float bf2f(unsigned short b) {
    return __uint_as_float(((unsigned)b) << 16);
}
__device__ __forceinline__ float fsigmoid(float x) {
    return __builtin_amdgcn_rcpf(1.f + __builtin_amdgcn_exp2f(-1.44269504f * x));
}
__device__ __forceinline__ float ftanh(float x) {
    return 1.f - 2.f * __builtin_amdgcn_rcpf(1.f + __builtin_amdgcn_exp2f(2.88539009f * x));
}

// ---------------- weight pack + bias prep ----------------
// W'[n'][k] = k<128 ? w_ih[n'][k] : w_hh[n'][k-128]   (n' = gate*128 + j)
// Frag order: kb=k>>5, quad=(k&31)>>3, e=k&7, tn=n'>>4, lane=quad*16+(n'&15);
// Bhi[((kb*32+tn)*64+lane)*8+e]; Blo only for k>=128. Chunk kb is a
// CONTIGUOUS 32 KB span -> cheap LDS staging in the gemm kernels.
__global__ __launch_bounds__(256) void pack_kernel(const float* __restrict__ w_ih,
                                                   const float* __restrict__ w_hh,
                                                   const float* __restrict__ b_ih,
                                                   const float* __restrict__ b_hh,
                                                   unsigned short* __restrict__ Bhi,
                                                   unsigned short* __restrict__ Blo,
                                                   float* __restrict__ bias) {
    const int idx = blockIdx.x * 256 + threadIdx.x;   // 131072 = 512 n' x 256 k
    const int k  = idx & 255;
    const int np = idx >> 8;
    const float val = (k < 128) ? w_ih[(size_t)np * 128 + k]
                                : w_hh[(size_t)np * 128 + (k - 128)];
    const unsigned short hi = f2bf(val);
    const int kb = k >> 5, krel = k & 31, quad = krel >> 3, e = krel & 7;
    const int tn = np >> 4, col = np & 15, lane = quad * 16 + col;
    Bhi[(((size_t)kb * 32 + tn) * 64 + lane) * 8 + e] = hi;
    if (kb >= 4) {
        const unsigned short lo = f2bf(val - bf2f(hi));
        Blo[((((size_t)kb - 4) * 32 + tn) * 64 + lane) * 8 + e] = lo;
    }
    if (k == 0) bias[np] = b_ih[np] + b_hh[np];
}

// ---------------- trunk: levels 0..6, one block per (tree, half) ----------
// Block covers half-tree rows [s*2^(d-1),(s+1)*2^(d-1)) at level d>=1;
// local parent of local row m is always m>>1 (root local 0). 8 B-stream
// iterations per block (1 per level + 2 at L6). h/c single-buffered in LDS:
// all reads (stage h-part + hoisted cpre) happen PRE-barrier, writes POST.
__global__ __launch_bounds__(512, 2) void trunk_kernel(
    const float* __restrict__ node_emb,
    const unsigned short* __restrict__ Bhi,
    const unsigned short* __restrict__ Blo,
    const float* __restrict__ bias,
    float* __restrict__ h6g, float* __restrict__ c6g)
{
    __shared__ float hbuf[32][132];               // 16.9 KB
    __shared__ float cbuf[32][132];               // 16.9 KB
    __shared__ unsigned short AhiF[8 * 2 * 512];  // 16 KB (2 tiles)
    __shared__ unsigned short AloF[4 * 2 * 512];  //  8 KB
    // Total 58368 B -> 2 blocks/CU possible.

    const int t    = blockIdx.x >> 1;
    const int s    = blockIdx.x & 1;
    const int tid  = threadIdx.x;
    const int widx = tid >> 6;
    const int lane = tid & 63;
    const int ml   = lane & 15;
    const int quad = lane >> 4;
    const int j    = widx * 16 + ml;

    const float bi = bias[j];
    const float bf = bias[128 + j];
    const float bg = bias[256 + j];
    const float bo = bias[384 + j];

    const short8* Bh8 = reinterpret_cast<const short8*>(Bhi);
    const short8* Bl8 = reinterpret_cast<const short8*>(Blo);
    const short8* Ah8 = reinterpret_cast<const short8*>(AhiF);
    const short8* Al8 = reinterpret_cast<const short8*>(AloF);

    for (int d = 0; d <= 6; ++d) {
        const int rows = (d == 0) ? 1 : (1 << (d - 1));

        // ---- PRE-barrier reads: hoisted cpre + A staging (reads hbuf) ----
        float cpre[2][4];
        #pragma unroll
        for (int mt = 0; mt < 2; ++mt)
            #pragma unroll
            for (int rr = 0; rr < 4; ++rr) {
                int m = mt * 16 + quad * 4 + rr;
                if (m > rows - 1) m = rows - 1;
                cpre[mt][rr] = (d == 0) ? 0.f : cbuf[m >> 1][j];
            }

        #pragma unroll
        for (int h2 = 0; h2 < 4; ++h2) {
            const int r  = tid >> 4;              // 0..31
            const int kq = tid & 15;
            const int k  = (kq + h2 * 16) * 4;    // 0..252
            int p = r; if (p > rows - 1) p = rows - 1;
            float4 v;
            if (k < 128) {
                const int pg   = (d == 0) ? 0 : ((s << (d - 1)) + p);
                const int node = (1 << d) - 1 + pg;
                v = *reinterpret_cast<const float4*>(
                        node_emb + (size_t)(t * NPT + node) * D_N + k);
            } else if (d == 0) {
                v = make_float4(0.f, 0.f, 0.f, 0.f);
            } else {
                v = *reinterpret_cast<const float4*>(&hbuf[p >> 1][k - 128]);
            }
            const int kb = k >> 5, qk = (k & 31) >> 3, e0 = k & 4;
            const int mt = r >> 4, mlr = r & 15;
            const ushort4v hv = { f2bf(v.x), f2bf(v.y), f2bf(v.z), f2bf(v.w) };
            *reinterpret_cast<ushort4v*>(
                &AhiF[((kb * 2 + mt) * 64 + qk * 16 + mlr) * 8 + e0]) = hv;
            if (k >= 128) {
                const ushort4v lv = { f2bf(v.x - bf2f(hv.x)), f2bf(v.y - bf2f(hv.y)),
                                      f2bf(v.z - bf2f(hv.z)), f2bf(v.w - bf2f(hv.w)) };
                *reinterpret_cast<ushort4v*>(
                    &AloF[(((kb - 4) * 2 + mt) * 64 + qk * 16 + mlr) * 8 + e0]) = lv;
            }
        }
        __syncthreads();

        // ---- MFMA: sequential M-tiles, R12-proven remat B-stream ----
        const int nmt = (rows > 16) ? 2 : 1;
        for (int mt = 0; mt < nmt; ++mt) {
            f32x4 acc[4];
            #pragma unroll
            for (int g = 0; g < 4; ++g) acc[g] = (f32x4)0.f;
            #pragma unroll
            for (int kb = 0; kb < 8; ++kb) {
                const short8 ah = Ah8[(kb * 2 + mt) * 64 + lane];
                short8 al;
                if (kb >= 4) al = Al8[((kb - 4) * 2 + mt) * 64 + lane];
                #pragma unroll
                for (int g = 0; g < 4; ++g) {
                    const short8 bh = Bh8[(kb * 32 + g * 8 + widx) * 64 + lane];
                    acc[g] = __builtin_amdgcn_mfma_f32_16x16x32_bf16(ah, bh, acc[g], 0, 0, 0);
                    if (kb >= 4) {
                        const short8 bl = Bl8[((kb - 4) * 32 + g * 8 + widx) * 64 + lane];
                        acc[g] = __builtin_amdgcn_mfma_f32_16x16x32_bf16(ah, bl, acc[g], 0, 0, 0);
                        acc[g] = __builtin_amdgcn_mfma_f32_16x16x32_bf16(al, bh, acc[g], 0, 0, 0);
                    }
                }
            }
            #pragma unroll
            for (int rr = 0; rr < 4; ++rr) {
                const int m = mt * 16 + quad * 4 + rr;
                if (m < rows) {
                    const float ig = fsigmoid(acc[0][rr] + bi);
                    const float fg = fsigmoid(acc[1][rr] + bf);
                    const float gv = ftanh(acc[2][rr] + bg);
                    const float og = fsigmoid(acc[3][rr] + bo);
                    const float cn = fg * cpre[mt][rr] + ig * gv;
                    const float hn = og * ftanh(cn);
                    hbuf[m][j] = hn;
                    cbuf[m][j] = cn;
                    if (d == 6) {
                        const size_t row = (size_t)(t * 64 + s * 32 + m) * D_N + j;
                        h6g[row] = hn;
                        c6g[row] = cn;
                    }
                }
            }
        }
        __syncthreads();
    }
}

// ---------------- gemm: one level (7 or 8) as a tiled GEMM ----------------
// BM=32 rows/block. B streamed once per block: per-kb 32 KB chunk copied
// global->LDS; hi and lo chunks as separate sub-phases sharing one buffer.
// acc[2][4] + bh[4] ~ 90 live VGPRs. LDS 56 KB -> 2 blocks/CU.
__global__ __launch_bounds__(512, 2) void gemm_kernel(
    const float* __restrict__ node_emb,
    const unsigned short* __restrict__ Bhi,
    const unsigned short* __restrict__ Blo,
    const float* __restrict__ bias,
    const float* __restrict__ hsrc,
    const float* __restrict__ csrc,
    float* __restrict__ hdst,
    float* __restrict__ cdst,          // null for level 8
    const int rpt_sh,                  // log2(rows per tree): 7 or 8
    const int node_off)                // 127 or 255
{
    __shared__ unsigned short AhiF[8 * 2 * 512];  // 16 KB
    __shared__ unsigned short AloF[4 * 2 * 512];  //  8 KB
    __shared__ int4 BL[2048];                     // 32 KB B chunk
    // Total 57344 B -> 2 blocks/CU possible.

    const int tid  = threadIdx.x;
    const int widx = tid >> 6;
    const int lane = tid & 63;
    const int ml   = lane & 15;
    const int quad = lane >> 4;
    const int j    = widx * 16 + ml;

    const int b0 = blockIdx.x * 32;               // global row base
    const int t  = b0 >> rpt_sh;
    const int q0 = b0 & ((1 << rpt_sh) - 1);
    const size_t nbase = (size_t)(t * NPT + node_off) * D_N;  // + q*128
    const size_t pbase = ((size_t)t << (rpt_sh - 1)) * D_N;   // + (q>>1)*128

    const float bi = bias[j];
    const float bf = bias[128 + j];
    const float bg = bias[256 + j];
    const float bo = bias[384 + j];

    const short8* Ah8 = reinterpret_cast<const short8*>(AhiF);
    const short8* Al8 = reinterpret_cast<const short8*>(AloF);
    const short8* BL8 = reinterpret_cast<const short8*>(BL);

    // ---- stage A (32 rows): x from node_emb, h-part split from hsrc ----
    #pragma unroll
    for (int h2 = 0; h2 < 4; ++h2) {
        const int r  = tid >> 4;                  // 0..31
        const int kq = tid & 15;
        const int k  = (kq + h2 * 16) * 4;
        const int q  = q0 + r;
        float4 v;
        if (k < 128)
            v = *reinterpret_cast<const float4*>(node_emb + nbase + (size_t)q * D_N + k);
        else
            v = *reinterpret_cast<const float4*>(hsrc + pbase + (size_t)(q >> 1) * D_N + (k - 128));
        const int kb = k >> 5, qk = (k & 31) >> 3, e0 = k & 4;
        const int mt = r >> 4, mlr = r & 15;
        const ushort4v hv = { f2bf(v.x), f2bf(v.y), f2bf(v.z), f2bf(v.w) };
        *reinterpret_cast<ushort4v*>(
            &AhiF[((kb * 2 + mt) * 64 + qk * 16 + mlr) * 8 + e0]) = hv;
        if (k >= 128) {
            const ushort4v lv = { f2bf(v.x - bf2f(hv.x)), f2bf(v.y - bf2f(hv.y)),
                                  f2bf(v.z - bf2f(hv.z)), f2bf(v.w - bf2f(hv.w)) };
            *reinterpret_cast<ushort4v*>(
                &AloF[(((kb - 4) * 2 + mt) * 64 + qk * 16 + mlr) * 8 + e0]) = lv;
        }
    }

    float cpre[2][4];
    #pragma unroll
    for (int mt = 0; mt < 2; ++mt)
        #pragma unroll
        for (int rr = 0; rr < 4; ++rr) {
            const int q = q0 + mt * 16 + quad * 4 + rr;
            cpre[mt][rr] = csrc[pbase + (size_t)(q >> 1) * D_N + j];
        }
    __syncthreads();

    f32x4 acc[2][4];
    #pragma unroll
    for (int mt = 0; mt < 2; ++mt)
        #pragma unroll
        for (int g = 0; g < 4; ++g) acc[mt][g] = (f32x4)0.f;

    #pragma unroll
    for (int kb = 0; kb < 8; ++kb) {
        // ---- HI sub-phase: Bhi chunk kb -> LDS; ah*bh (+ al*bh) ----
        {
            const int4* src = reinterpret_cast<const int4*>(Bhi) + kb * 2048;
            #pragma unroll
            for (int c = 0; c < 4; ++c) BL[tid + c * 512] = src[tid + c * 512];
        }
        __syncthreads();
        {
            short8 bh[4];
            #pragma unroll
            for (int g = 0; g < 4; ++g) bh[g] = BL8[(g * 8 + widx) * 64 + lane];
            #pragma unroll
            for (int mt = 0; mt < 2; ++mt) {
                const short8 ah = Ah8[(kb * 2 + mt) * 64 + lane];
                #pragma unroll
                for (int g = 0; g < 4; ++g)
                    acc[mt][g] = __builtin_amdgcn_mfma_f32_16x16x32_bf16(ah, bh[g], acc[mt][g], 0, 0, 0);
                if (kb >= 4) {
                    const short8 al = Al8[((kb - 4) * 2 + mt) * 64 + lane];
                    #pragma unroll
                    for (int g = 0; g < 4; ++g)
                        acc[mt][g] = __builtin_amdgcn_mfma_f32_16x16x32_bf16(al, bh[g], acc[mt][g], 0, 0, 0);
                }
            }
        }
        __syncthreads();
        // ---- LO sub-phase (kb>=4): Blo chunk -> LDS; ah*bl ----
        if (kb >= 4) {
            {
                const int4* src = reinterpret_cast<const int4*>(Blo) + (kb - 4) * 2048;
                #pragma unroll
                for (int c = 0; c < 4; ++c) BL[tid + c * 512] = src[tid + c * 512];
            }
            __syncthreads();
            {
                short8 bl[4];
                #pragma unroll
                for (int g = 0; g < 4; ++g) bl[g] = BL8[(g * 8 + widx) * 64 + lane];
                #pragma unroll
                for (int mt = 0; mt < 2; ++mt) {
                    const short8 ah = Ah8[(kb * 2 + mt) * 64 + lane];
                    #pragma unroll
                    for (int g = 0; g < 4; ++g)
                        acc[mt][g] = __builtin_amdgcn_mfma_f32_16x16x32_bf16(ah, bl[g], acc[mt][g], 0, 0, 0);
                }
            }
            __syncthreads();
        }
    }

    // ---- LSTM epilogue ----
    #pragma unroll
    for (int mt = 0; mt < 2; ++mt)
        #pragma unroll
        for (int rr = 0; rr < 4; ++rr) {
            const int m  = mt * 16 + quad * 4 + rr;
            const float ig = fsigmoid(acc[mt][0][rr] + bi);
            const float fg = fsigmoid(acc[mt][1][rr] + bf);
            const float gv = ftanh(acc[mt][2][rr] + bg);
            const float og = fsigmoid(acc[mt][3][rr] + bo);
            const float cn = fg * cpre[mt][rr] + ig * gv;
            const float hn = og * ftanh(cn);
            const size_t row = (size_t)(b0 + m) * D_N + j;
            hdst[row] = hn;
            if (cdst) cdst[row] = cn;
        }
}

// ---------------- fused leaf-extract + gather ----------------
__global__ __launch_bounds__(256) void gather_kernel(const float* __restrict__ cross,
                                                     const float* __restrict__ h8,
                                                     float* __restrict__ out) {
    const int bt   = blockIdx.x * 4 + (threadIdx.x >> 6);
    const int lane = threadIdx.x & 63;
    const int t    = bt % T_N;
    const float4 v = reinterpret_cast<const float4*>(cross + (size_t)bt * L_N)[lane];
    int idx = -1;
    if      (v.x > 0.f) idx = lane * 4 + 0;
    else if (v.y > 0.f) idx = lane * 4 + 1;
    else if (v.z > 0.f) idx = lane * 4 + 2;
    else if (v.w > 0.f) idx = lane * 4 + 3;
    const unsigned long long m = __ballot(idx >= 0);
    int lf = -1;
    if (m != 0ULL) {
        const int first = __builtin_ctzll(m);
        lf = __shfl(idx, first);
    }
    float2 o = make_float2(0.f, 0.f);
    if (lf >= 0)
        o = reinterpret_cast<const float2*>(h8 + (size_t)(t * L_N + lf) * D_N)[lane];
    reinterpret_cast<float2*>(out + (size_t)bt * D_N)[lane] = o;
}

extern "C" void kernel_launch(void* const* d_in, const int* in_sizes, int n_in,
                              void* d_out, int out_size, void* d_ws, size_t ws_size,
                              hipStream_t stream) {
    const float* cross    = (const float*)d_in[0];
    const float* node_emb = (const float*)d_in[1];
    const float* w_ih     = (const float*)d_in[2];
    const float* w_hh     = (const float*)d_in[3];
    const float* b_ih     = (const float*)d_in[4];
    const float* b_hh     = (const float*)d_in[5];
    float* out = (float*)d_out;
    float* ws  = (float*)d_ws;

    // ws layout (floats) -- identical footprint to the proven layout:
    // h8[25600*128], h7g[12800*128], c7g[12800*128], bias[512],
    // Bhi[131072 u16], Blo[65536 u16].
    float* h8   = ws;
    float* h7g  = h8 + (size_t)25600 * D_N;
    float* c7g  = h7g + (size_t)12800 * D_N;
    float* bias = c7g + (size_t)12800 * D_N;
    unsigned short* Bhi = (unsigned short*)(bias + 512);
    unsigned short* Blo = Bhi + 131072;
    // h6g/c6g alias the FRONT of h8: dead once gemm7 finishes; gemm8
    // overwrites the region with final h8 values afterwards (stream order).
    float* c6g = h8;                               // rows [0, 6400)
    float* h6g = h8 + (size_t)6400 * D_N;          // rows [6400, 12800)

    pack_kernel<<<512, 256, 0, stream>>>(w_ih, w_hh, b_ih, b_hh, Bhi, Blo, bias);

    // levels 0..6: one block per (tree, half-tree)
    trunk_kernel<<<2 * T_N, 512, 0, stream>>>(node_emb, Bhi, Blo, bias, h6g, c6g);

    // level 7: M = 12800 rows, BM=32 -> 400 blocks
    gemm_kernel<<<400, 512, 0, stream>>>(node_emb, Bhi, Blo, bias,
                                         h6g, c6g, h7g, c7g, 7, 127);

    // level 8: M = 25600 rows -> 800 blocks (writes h8, incl. aliased front)
    gemm_kernel<<<800, 512, 0, stream>>>(node_emb, Bhi, Blo, bias,
                                         h7g, c7g, h8, nullptr, 8, 255);

    // fused leaf+gather
    gather_kernel<<<(B_N * T_N) / 4, 256, 0, stream>>>(cross, h8, out);
}